// Round 6
// baseline (4017.647 us; speedup 1.0000x reference)
//
#include <hip/hip_runtime.h>
#include <stdint.h>
#include <stddef.h>

// Problem dims
#define B_  128
#define S_  48
#define E_  620
#define EP  640    // E padded to multiple of 32 (zeros)
#define H_  2400
#define N3  7200   // 3*H (r,i,n concatenated)
#define KH  2400
#define NBLK 225   // persistent blocks: 7200 / 32 rows, 1 block/CU (LDS-bound)
#define P1_ITERS 20  // phase-1 K = 640 = 20 x 32
#define P2_ITERS 75  // phase-2 K = 2400 = 75 x 32

typedef _Float16 half_t;
typedef __attribute__((ext_vector_type(8))) _Float16 half8;
typedef __attribute__((ext_vector_type(4))) float    floatx4;

// Workgroup barrier that waits ONLY on LDS ops; in-flight global loads keep
// flying. 0xC07F = vmcnt(63) expcnt(7) lgkmcnt(0).
__device__ __forceinline__ void lds_barrier() {
  __builtin_amdgcn_sched_barrier(0);
  __builtin_amdgcn_s_waitcnt(0xC07F);
  __builtin_amdgcn_s_barrier();
  __builtin_amdgcn_sched_barrier(0);
}

// Device-scope grid barrier (all NBLK blocks co-resident: 225 < 256 CUs).
__device__ __forceinline__ void grid_barrier(int* bar) {
  __syncthreads();
  if (threadIdx.x == 0) {
    __threadfence();   // agent-scope release: flush L1/L2 writes
    int g = __hip_atomic_load(&bar[1], __ATOMIC_RELAXED, __HIP_MEMORY_SCOPE_AGENT);
    if (__hip_atomic_fetch_add(&bar[0], 1, __ATOMIC_ACQ_REL,
                               __HIP_MEMORY_SCOPE_AGENT) == NBLK - 1) {
      __hip_atomic_store(&bar[0], 0, __ATOMIC_RELAXED, __HIP_MEMORY_SCOPE_AGENT);
      __hip_atomic_fetch_add(&bar[1], 1, __ATOMIC_ACQ_REL, __HIP_MEMORY_SCOPE_AGENT);
    } else {
      while (__hip_atomic_load(&bar[1], __ATOMIC_RELAXED,
                               __HIP_MEMORY_SCOPE_AGENT) == g)
        __builtin_amdgcn_s_sleep(2);
    }
    __threadfence();   // agent-scope acquire: invalidate stale caches
  }
  __syncthreads();
}

// ---- x = fp16(emb[tokens]), padded [6144, 640] ----
__global__ void gather_cast_x(const int* __restrict__ tokens,
                              const float* __restrict__ emb,
                              half_t* __restrict__ xb) {
  int idx = blockIdx.x * 256 + threadIdx.x;       // over 6144*EP
  int m = idx / EP, c = idx - m * EP;
  float v = 0.f;
  if (c < E_) v = emb[(size_t)tokens[m] * E_ + c];
  xb[idx] = (half_t)v;
}

// ---- W_i = fp16 concat(W_ir,W_ii,W_in) [7200, 640]; bias concat [7200] ----
__global__ void convert_wi(const float* __restrict__ Wir, const float* __restrict__ Wii,
                           const float* __restrict__ Win,
                           const float* __restrict__ bir, const float* __restrict__ bii,
                           const float* __restrict__ bin,
                           half_t* __restrict__ Wi, float* __restrict__ bias) {
  int idx = blockIdx.x * 256 + threadIdx.x;       // over N3*EP
  int r = idx / EP, c = idx - r * EP;
  const float* W = (r < H_) ? Wir : (r < 2*H_ ? Wii : Win);
  int rr = (r < H_) ? r : (r < 2*H_ ? r - H_ : r - 2*H_);
  float v = (c < E_) ? W[(size_t)rr * E_ + c] : 0.f;
  Wi[idx] = (half_t)v;
  if (c == 0) {
    const float* bb = (r < H_) ? bir : (r < 2*H_ ? bii : bin);
    bias[r] = bb[rr];
  }
}

// ---- Wf = fp16 concat(W_hr,W_hi,W_hn) [7200, 2400] ----
__global__ void convert_wh(const float* __restrict__ Whr, const float* __restrict__ Whi,
                           const float* __restrict__ Whn, half_t* __restrict__ Wf) {
  int idx = blockIdx.x * 256 + threadIdx.x;       // over N3*KH
  int r = idx / KH, c = idx - r * KH;
  const float* W = (r < H_) ? Whr : (r < 2*H_ ? Whi : Whn);
  int rr = (r < H_) ? r : (r < 2*H_ ? r - H_ : r - 2*H_);
  Wf[idx] = (half_t)W[(size_t)rr * KH + c];
}

__global__ void init_h(float* __restrict__ h, half_t* __restrict__ hh,
                       int* __restrict__ bar) {
  int idx = blockIdx.x * 256 + threadIdx.x;       // over B_*H_
  h[idx] = 0.f;
  hh[idx] = (half_t)0.f;
  if (idx == 0) { bar[0] = 0; bar[1] = 0; }
}

// ---- Phase 1: gx = fp16( xb @ Wi^T + bias )  [6144 x 7200], K=640 ----
// 128x128 tile, 4 waves (64x64 each), fragment-major LDS double-buffered,
// VGPR prefetch depth 2, lgkm-only barrier. (r5 structure, fp16 operands.)
__global__ __launch_bounds__(256, 2) void gemm_x(
    const half_t* __restrict__ A,   // xb [6144 x 640]
    const half_t* __restrict__ Bm,  // Wi [7200 x 640]
    half_t* __restrict__ C,         // gx [6144 x 7200]
    const float* __restrict__ bias)
{
  __shared__ half_t As[2][4096];   // 8 KB buffers: 128 rows x 32 k, frag-major
  __shared__ half_t Bs[2][4096];

  const int tid = threadIdx.x;
  const int lane = tid & 63;
  const int w = tid >> 6;
  const int m0 = blockIdx.x * 128;
  const int n0 = blockIdx.y * 128;
  const int wm = (w >> 1) * 64, wn = (w & 1) * 64;

  const int c0 = tid, c1 = tid + 256;
  const int rA0 = m0 + (c0 >> 6) * 16 + (c0 & 15), q0 = ((c0 >> 4) & 3) * 8;
  const int rA1 = m0 + (c1 >> 6) * 16 + (c1 & 15), q1 = ((c1 >> 4) & 3) * 8;
  int rB0 = n0 + (c0 >> 6) * 16 + (c0 & 15); if (rB0 >= N3) rB0 = N3 - 1;
  int rB1 = n0 + (c1 >> 6) * 16 + (c1 & 15); if (rB1 >= N3) rB1 = N3 - 1;
  const half_t* pA0 = A  + (size_t)rA0 * EP + q0;
  const half_t* pA1 = A  + (size_t)rA1 * EP + q1;
  const half_t* pB0 = Bm + (size_t)rB0 * EP + q0;
  const half_t* pB1 = Bm + (size_t)rB1 * EP + q1;

  floatx4 acc[4][4] = {};

  half8 ga0 = *(const half8*)(pA0);
  half8 ga1 = *(const half8*)(pA1);
  half8 gb0 = *(const half8*)(pB0);
  half8 gb1 = *(const half8*)(pB1);
  *(half8*)(As[0] + c0 * 8) = ga0;
  *(half8*)(As[0] + c1 * 8) = ga1;
  *(half8*)(Bs[0] + c0 * 8) = gb0;
  *(half8*)(Bs[0] + c1 * 8) = gb1;
  ga0 = *(const half8*)(pA0 + 32);
  ga1 = *(const half8*)(pA1 + 32);
  gb0 = *(const half8*)(pB0 + 32);
  gb1 = *(const half8*)(pB1 + 32);
  lds_barrier();

  #pragma unroll
  for (int i = 0; i < P1_ITERS; ++i) {
    const int cur = i & 1, nxt = cur ^ 1;
    half8 a[4], b[4];
    #pragma unroll
    for (int f = 0; f < 4; ++f) {
      a[f] = *(const half8*)(As[cur] + (((wm >> 4) + f) * 64 + lane) * 8);
      b[f] = *(const half8*)(Bs[cur] + (((wn >> 4) + f) * 64 + lane) * 8);
    }
    if (i + 1 < P1_ITERS) {
      *(half8*)(As[nxt] + c0 * 8) = ga0;
      *(half8*)(As[nxt] + c1 * 8) = ga1;
      *(half8*)(Bs[nxt] + c0 * 8) = gb0;
      *(half8*)(Bs[nxt] + c1 * 8) = gb1;
    }
    if (i + 2 < P1_ITERS) {
      int ko = (i + 2) * 32;
      ga0 = *(const half8*)(pA0 + ko);
      ga1 = *(const half8*)(pA1 + ko);
      gb0 = *(const half8*)(pB0 + ko);
      gb1 = *(const half8*)(pB1 + ko);
    }
    #pragma unroll
    for (int mf = 0; mf < 4; ++mf)
      #pragma unroll
      for (int nf = 0; nf < 4; ++nf)
        acc[mf][nf] = __builtin_amdgcn_mfma_f32_16x16x32_f16(
            a[mf], b[nf], acc[mf][nf], 0, 0, 0);
    if (i + 1 < P1_ITERS) lds_barrier();
  }

  const int col = lane & 15, qr = (lane >> 4) * 4;
  #pragma unroll
  for (int nf = 0; nf < 4; ++nf) {
    int n = n0 + wn + nf * 16 + col;
    if (n >= N3) continue;
    float bv = bias[n];
    #pragma unroll
    for (int mf = 0; mf < 4; ++mf)
      #pragma unroll
      for (int r = 0; r < 4; ++r)
        C[(size_t)(m0 + wm + mf * 16 + qr + r) * N3 + n] =
            (half_t)(acc[mf][nf][r] + bv);
  }
}

// ---- Phase 2: persistent weight-stationary GRU scan ----
// 225 blocks x 256 threads, 1 block/CU (150 KiB LDS). Block b owns weight
// rows [32b, 32b+32) x K=2400 fp16 in LDS (frag-major), loaded ONCE.
// Per step: G[:, slice] = hh @ Ws^T (A-frags from global/L2, depth-4 ring;
// B-frags ds_read_b128 conflict-free), grid barrier, fused gate update,
// grid barrier. No per-step launches, no weight re-streaming.
__global__ __launch_bounds__(256, 1) void gru_scan(
    const half_t* __restrict__ Wf,   // [7200][2400]
    const half_t* __restrict__ gx,   // [6144][7200]
    float* __restrict__ G,           // [128][7200] scratch
    float* __restrict__ h,           // [128][2400]
    half_t* __restrict__ hh,         // [128][2400]
    const int* __restrict__ lengths,
    float* __restrict__ out,         // [128][2400]
    int* __restrict__ bar)
{
  __shared__ half_t Ws[76800];   // 150 KiB: 32 rows x 2400 k, frag-major

  const int tid = threadIdx.x;
  const int lane = tid & 63;
  const int w = tid >> 6;
  const int n0 = blockIdx.x * 32;

  // one-time weight load: chunk c = kt*128 + nt*64 + l
  for (int c = tid; c < 9600; c += 256) {
    int kt = c >> 7, rem = c & 127;
    int nt = rem >> 6, l = rem & 63;
    int n = n0 + nt * 16 + (l & 15);
    int k = kt * 32 + (l >> 4) * 8;
    *(half8*)&Ws[c * 8] = *(const half8*)&Wf[(size_t)n * KH + k];
  }
  __syncthreads();

  const int am = lane & 15;
  const int ak = (lane >> 4) * 8;
  const half_t* pa0 = hh + (size_t)((2 * w)     * 16 + am) * KH + ak;
  const half_t* pa1 = hh + (size_t)((2 * w + 1) * 16 + am) * KH + ak;
  const int col = lane & 15, qr = (lane >> 4) * 4;

  for (int t = 0; t < S_; ++t) {
    // ---- compute: wave w does m-tiles {2w,2w+1} x n-tiles {0,1} ----
    floatx4 acc[2][2] = {};
    half8 aR[4][2], bR[4][2];
    #pragma unroll
    for (int i = 0; i < 4; ++i) {
      aR[i][0] = *(const half8*)(pa0 + i * 32);
      aR[i][1] = *(const half8*)(pa1 + i * 32);
      bR[i][0] = *(const half8*)&Ws[(i * 128 + lane) * 8];
      bR[i][1] = *(const half8*)&Ws[(i * 128 + 64 + lane) * 8];
    }
    #pragma unroll
    for (int i = 0; i < P2_ITERS; ++i) {
      const int s = i & 3;
      half8 a0 = aR[s][0], a1 = aR[s][1];
      half8 b0 = bR[s][0], b1 = bR[s][1];
      if (i + 4 < P2_ITERS) {
        int ko = (i + 4) * 32;
        aR[s][0] = *(const half8*)(pa0 + ko);
        aR[s][1] = *(const half8*)(pa1 + ko);
        bR[s][0] = *(const half8*)&Ws[((i + 4) * 128 + lane) * 8];
        bR[s][1] = *(const half8*)&Ws[((i + 4) * 128 + 64 + lane) * 8];
      }
      acc[0][0] = __builtin_amdgcn_mfma_f32_16x16x32_f16(a0, b0, acc[0][0], 0, 0, 0);
      acc[0][1] = __builtin_amdgcn_mfma_f32_16x16x32_f16(a0, b1, acc[0][1], 0, 0, 0);
      acc[1][0] = __builtin_amdgcn_mfma_f32_16x16x32_f16(a1, b0, acc[1][0], 0, 0, 0);
      acc[1][1] = __builtin_amdgcn_mfma_f32_16x16x32_f16(a1, b1, acc[1][1], 0, 0, 0);
    }
    #pragma unroll
    for (int mf = 0; mf < 2; ++mf)
      #pragma unroll
      for (int nf = 0; nf < 2; ++nf)
        #pragma unroll
        for (int r = 0; r < 4; ++r)
          G[(size_t)((2 * w + mf) * 16 + qr + r) * N3 + n0 + nf * 16 + col] =
              acc[mf][nf][r];

    grid_barrier(bar);

    // ---- fused gate update (grid-strided over B_*H_) ----
    for (int idx = blockIdx.x * 256 + tid; idx < B_ * H_; idx += NBLK * 256) {
      int m = idx / H_;
      int j = idx - m * H_;
      size_t rx = ((size_t)m * S_ + t) * N3;
      float xr = (float)gx[rx + j];
      float xi = (float)gx[rx + H_ + j];
      float xn = (float)gx[rx + 2 * H_ + j];
      size_t gm = (size_t)m * N3;
      float Gr = G[gm + j], Gi = G[gm + H_ + j], Gn = G[gm + 2 * H_ + j];
      float ho = h[idx];
      float r  = 1.f / (1.f + __expf(-(xr + Gr)));
      float ig = 1.f / (1.f + __expf(-(xi + Gi)));
      float nn = tanhf(xn + r * Gn);
      float hn = (1.f - ig) * nn + ig * ho;
      h[idx]  = hn;
      hh[idx] = (half_t)hn;
      int lc = lengths[m] - 1;
      lc = lc < 0 ? 0 : (lc > S_ - 1 ? S_ - 1 : lc);
      if (t == lc) out[idx] = hn;
    }

    grid_barrier(bar);
  }
}

extern "C" void kernel_launch(void* const* d_in, const int* in_sizes, int n_in,
                              void* d_out, int out_size, void* d_ws, size_t ws_size,
                              hipStream_t stream)
{
  const int*   tokens  = (const int*)d_in[0];
  const int*   lengths = (const int*)d_in[1];
  const float* emb = (const float*)d_in[2];
  const float* Wir = (const float*)d_in[3];
  const float* Wii = (const float*)d_in[4];
  const float* Win = (const float*)d_in[5];
  const float* bir = (const float*)d_in[6];
  const float* bii = (const float*)d_in[7];
  const float* bin = (const float*)d_in[8];
  const float* Whr = (const float*)d_in[9];
  const float* Whi = (const float*)d_in[10];
  const float* Whn = (const float*)d_in[11];
  float* out = (float*)d_out;

  char* ws = (char*)d_ws;
  size_t off = 0;
  auto alloc = [&](size_t bytes) {
    void* p = ws + off;
    off = (off + bytes + 255) & ~(size_t)255;
    return p;
  };
  half_t* xb   = (half_t*)alloc((size_t)(B_ * S_) * EP * 2);   //  7.9 MB
  half_t* Wi   = (half_t*)alloc((size_t)N3 * EP * 2);          //  9.2 MB
  half_t* Wf   = (half_t*)alloc((size_t)N3 * KH * 2);          // 34.6 MB
  float*  bias = (float*)alloc((size_t)N3 * 4);
  half_t* gx   = (half_t*)alloc((size_t)(B_ * S_) * N3 * 2);   // 88.5 MB
  float*  G    = (float*)alloc((size_t)B_ * N3 * 4);           //  3.7 MB
  float*  h    = (float*)alloc((size_t)B_ * H_ * 4);
  half_t* hh   = (half_t*)alloc((size_t)B_ * H_ * 2);
  int*    bar  = (int*)alloc(256);

  gather_cast_x<<<(B_ * S_ * EP) / 256, 256, 0, stream>>>(tokens, emb, xb);
  convert_wi<<<(N3 * EP) / 256, 256, 0, stream>>>(Wir, Wii, Win, bir, bii, bin, Wi, bias);
  convert_wh<<<(N3 * KH) / 256, 256, 0, stream>>>(Whr, Whi, Whn, Wf);
  init_h<<<(B_ * H_) / 256, 256, 0, stream>>>(h, hh, bar);

  // Phase 1: gates_x = fp16( x @ W_i^T + b )   [6144 x 7200]
  gemm_x<<<dim3(48, 57), 256, 0, stream>>>(xb, Wi, gx, bias);

  // Phase 2: one persistent kernel runs all 48 steps
  gru_scan<<<NBLK, 256, 0, stream>>>(Wf, gx, G, h, hh, lengths, out, bar);
}

// Round 7
// 1780.073 us; speedup vs baseline: 2.2570x; 2.2570x over previous
//
#include <hip/hip_runtime.h>
#include <stdint.h>
#include <stddef.h>

// Problem dims
#define B_  128
#define S_  48
#define E_  620
#define EP  640    // E padded to multiple of 32 (zeros)
#define H_  2400
#define N3  7200   // 3*H (r,i,n concatenated)
#define KH  2400
#define ZSPLIT 5     // phase-2 k-split: 5 chunks x 480 (15 iters of 32)
#define P2_ITERS 15
#define P1_ITERS 20  // phase-1 K = 640 = 20 x 32

typedef _Float16 half_t;
typedef __attribute__((ext_vector_type(8))) _Float16 half8;
typedef __attribute__((ext_vector_type(4))) float    floatx4;

// Workgroup barrier that waits ONLY on LDS ops; in-flight global loads keep
// flying. 0xC07F = vmcnt(63) expcnt(7) lgkmcnt(0).  (phase-1 only)
__device__ __forceinline__ void lds_barrier() {
  __builtin_amdgcn_sched_barrier(0);
  __builtin_amdgcn_s_waitcnt(0xC07F);
  __builtin_amdgcn_s_barrier();
  __builtin_amdgcn_sched_barrier(0);
}

// ---- x = fp16(emb[tokens]), padded [6144, 640] ----
__global__ void gather_cast_x(const int* __restrict__ tokens,
                              const float* __restrict__ emb,
                              half_t* __restrict__ xb) {
  int idx = blockIdx.x * 256 + threadIdx.x;       // over 6144*EP
  int m = idx / EP, c = idx - m * EP;
  float v = 0.f;
  if (c < E_) v = emb[(size_t)tokens[m] * E_ + c];
  xb[idx] = (half_t)v;
}

// ---- W_i = fp16 concat(W_ir,W_ii,W_in) [7200, 640]; bias concat [7200] ----
__global__ void convert_wi(const float* __restrict__ Wir, const float* __restrict__ Wii,
                           const float* __restrict__ Win,
                           const float* __restrict__ bir, const float* __restrict__ bii,
                           const float* __restrict__ bin,
                           half_t* __restrict__ Wi, float* __restrict__ bias) {
  int idx = blockIdx.x * 256 + threadIdx.x;       // over N3*EP
  int r = idx / EP, c = idx - r * EP;
  const float* W = (r < H_) ? Wir : (r < 2*H_ ? Wii : Win);
  int rr = (r < H_) ? r : (r < 2*H_ ? r - H_ : r - 2*H_);
  float v = (c < E_) ? W[(size_t)rr * E_ + c] : 0.f;
  Wi[idx] = (half_t)v;
  if (c == 0) {
    const float* bb = (r < H_) ? bir : (r < 2*H_ ? bii : bin);
    bias[r] = bb[rr];
  }
}

// ---- Wf = fp16 concat(W_hr,W_hi,W_hn) [7200, 2400] ----
__global__ void convert_wh(const float* __restrict__ Whr, const float* __restrict__ Whi,
                           const float* __restrict__ Whn, half_t* __restrict__ Wf) {
  int idx = blockIdx.x * 256 + threadIdx.x;       // over N3*KH
  int r = idx / KH, c = idx - r * KH;
  const float* W = (r < H_) ? Whr : (r < 2*H_ ? Whi : Whn);
  int rr = (r < H_) ? r : (r < 2*H_ ? r - H_ : r - 2*H_);
  Wf[idx] = (half_t)W[(size_t)rr * KH + c];
}

__global__ void init_h(float* __restrict__ h, half_t* __restrict__ hh) {
  int idx = blockIdx.x * 256 + threadIdx.x;       // over B_*H_
  h[idx] = 0.f;
  hh[idx] = (half_t)0.f;
}

// ---- Phase 1: gx = fp16( xb @ Wi^T + bias )  [6144 x 7200], K=640 ----
// (r5/r6 structure: 128x128 tile, frag-major LDS dbuf, lgkm-only barrier.)
__global__ __launch_bounds__(256, 2) void gemm_x(
    const half_t* __restrict__ A,   // xb [6144 x 640]
    const half_t* __restrict__ Bm,  // Wi [7200 x 640]
    half_t* __restrict__ C,         // gx [6144 x 7200]
    const float* __restrict__ bias)
{
  __shared__ half_t As[2][4096];
  __shared__ half_t Bs[2][4096];

  const int tid = threadIdx.x;
  const int lane = tid & 63;
  const int w = tid >> 6;
  const int m0 = blockIdx.x * 128;
  const int n0 = blockIdx.y * 128;
  const int wm = (w >> 1) * 64, wn = (w & 1) * 64;

  const int c0 = tid, c1 = tid + 256;
  const int rA0 = m0 + (c0 >> 6) * 16 + (c0 & 15), q0 = ((c0 >> 4) & 3) * 8;
  const int rA1 = m0 + (c1 >> 6) * 16 + (c1 & 15), q1 = ((c1 >> 4) & 3) * 8;
  int rB0 = n0 + (c0 >> 6) * 16 + (c0 & 15); if (rB0 >= N3) rB0 = N3 - 1;
  int rB1 = n0 + (c1 >> 6) * 16 + (c1 & 15); if (rB1 >= N3) rB1 = N3 - 1;
  const half_t* pA0 = A  + (size_t)rA0 * EP + q0;
  const half_t* pA1 = A  + (size_t)rA1 * EP + q1;
  const half_t* pB0 = Bm + (size_t)rB0 * EP + q0;
  const half_t* pB1 = Bm + (size_t)rB1 * EP + q1;

  floatx4 acc[4][4] = {};

  half8 ga0 = *(const half8*)(pA0);
  half8 ga1 = *(const half8*)(pA1);
  half8 gb0 = *(const half8*)(pB0);
  half8 gb1 = *(const half8*)(pB1);
  *(half8*)(As[0] + c0 * 8) = ga0;
  *(half8*)(As[0] + c1 * 8) = ga1;
  *(half8*)(Bs[0] + c0 * 8) = gb0;
  *(half8*)(Bs[0] + c1 * 8) = gb1;
  ga0 = *(const half8*)(pA0 + 32);
  ga1 = *(const half8*)(pA1 + 32);
  gb0 = *(const half8*)(pB0 + 32);
  gb1 = *(const half8*)(pB1 + 32);
  lds_barrier();

  #pragma unroll
  for (int i = 0; i < P1_ITERS; ++i) {
    const int cur = i & 1, nxt = cur ^ 1;
    half8 a[4], b[4];
    #pragma unroll
    for (int f = 0; f < 4; ++f) {
      a[f] = *(const half8*)(As[cur] + (((wm >> 4) + f) * 64 + lane) * 8);
      b[f] = *(const half8*)(Bs[cur] + (((wn >> 4) + f) * 64 + lane) * 8);
    }
    if (i + 1 < P1_ITERS) {
      *(half8*)(As[nxt] + c0 * 8) = ga0;
      *(half8*)(As[nxt] + c1 * 8) = ga1;
      *(half8*)(Bs[nxt] + c0 * 8) = gb0;
      *(half8*)(Bs[nxt] + c1 * 8) = gb1;
    }
    if (i + 2 < P1_ITERS) {
      int ko = (i + 2) * 32;
      ga0 = *(const half8*)(pA0 + ko);
      ga1 = *(const half8*)(pA1 + ko);
      gb0 = *(const half8*)(pB0 + ko);
      gb1 = *(const half8*)(pB1 + ko);
    }
    #pragma unroll
    for (int mf = 0; mf < 4; ++mf)
      #pragma unroll
      for (int nf = 0; nf < 4; ++nf)
        acc[mf][nf] = __builtin_amdgcn_mfma_f32_16x16x32_f16(
            a[mf], b[nf], acc[mf][nf], 0, 0, 0);
    if (i + 1 < P1_ITERS) lds_barrier();
  }

  const int col = lane & 15, qr = (lane >> 4) * 4;
  #pragma unroll
  for (int nf = 0; nf < 4; ++nf) {
    int n = n0 + wn + nf * 16 + col;
    if (n >= N3) continue;
    float bv = bias[n];
    #pragma unroll
    for (int mf = 0; mf < 4; ++mf)
      #pragma unroll
      for (int r = 0; r < 4; ++r)
        C[(size_t)(m0 + wm + mf * 16 + qr + r) * N3 + n] =
            (half_t)(acc[mf][nf][r] + bv);
  }
}

// ---- Phase 2 GEMM: Gp[z] = hh(128 x 480-chunk) @ Wf^T, NO LDS, NO barriers.
// A (hh, 614 KB) is L2-hot; B (Wf, 34.6 MB/step) streams from L3. Both go
// straight global -> VGPR fragment rings (B depth-4, A depth-2); waves are
// fully independent so the compiler pipelines with fine-grained vmcnt.
// Block 256 thr = 4 waves (2m x 2n), tile 128x64, wave-tile 64x32.
// Grid (113 n-blocks, 5 k-chunks) = 565 blocks (~2.2/CU).
__global__ __launch_bounds__(256, 3) void gemm_h(
    const half_t* __restrict__ Ah,  // hh [128 x 2400]
    const half_t* __restrict__ Wf,  // [7200 x 2400]
    float* __restrict__ Gp)         // [ZSPLIT][128][7200]
{
  const int tid = threadIdx.x;
  const int lane = tid & 63;
  const int w = tid >> 6;
  const int n0 = blockIdx.x * 64;
  const int z  = blockIdx.y;
  const int kb = z * 480;
  const int wm = (w & 1) * 64;      // wave m-offset (0/64)
  const int wn = (w >> 1) * 32;     // wave n-offset (0/32)

  const int fm = lane & 15;         // frag row within 16
  const int fk = (lane >> 4) * 8;   // frag k-offset

  const half_t* pA = Ah + (size_t)(wm + fm) * KH + kb + fk;        // + f*16*KH
  int nB0 = n0 + wn + fm;      if (nB0 >= N3) nB0 = N3 - 1;
  int nB1 = n0 + wn + 16 + fm; if (nB1 >= N3) nB1 = N3 - 1;
  const half_t* pB0 = Wf + (size_t)nB0 * KH + kb + fk;
  const half_t* pB1 = Wf + (size_t)nB1 * KH + kb + fk;

  floatx4 acc[4][2] = {};   // 32 regs (AGPR-eligible)

  half8 aR[2][4];           // A ring, depth 2
  half8 bR[4][2];           // B ring, depth 4
  #pragma unroll
  for (int d = 0; d < 2; ++d)
    #pragma unroll
    for (int f = 0; f < 4; ++f)
      aR[d][f] = *(const half8*)(pA + f * 16 * KH + d * 32);
  #pragma unroll
  for (int d = 0; d < 4; ++d) {
    bR[d][0] = *(const half8*)(pB0 + d * 32);
    bR[d][1] = *(const half8*)(pB1 + d * 32);
  }

  #pragma unroll
  for (int i = 0; i < P2_ITERS; ++i) {
    half8 a0 = aR[i & 1][0], a1 = aR[i & 1][1];
    half8 a2 = aR[i & 1][2], a3 = aR[i & 1][3];
    half8 b0 = bR[i & 3][0], b1 = bR[i & 3][1];
    if (i + 2 < P2_ITERS) {
      int ko = (i + 2) * 32;
      #pragma unroll
      for (int f = 0; f < 4; ++f)
        aR[i & 1][f] = *(const half8*)(pA + f * 16 * KH + ko);
    }
    if (i + 4 < P2_ITERS) {
      int ko = (i + 4) * 32;
      bR[i & 3][0] = *(const half8*)(pB0 + ko);
      bR[i & 3][1] = *(const half8*)(pB1 + ko);
    }
    acc[0][0] = __builtin_amdgcn_mfma_f32_16x16x32_f16(a0, b0, acc[0][0], 0, 0, 0);
    acc[1][0] = __builtin_amdgcn_mfma_f32_16x16x32_f16(a1, b0, acc[1][0], 0, 0, 0);
    acc[2][0] = __builtin_amdgcn_mfma_f32_16x16x32_f16(a2, b0, acc[2][0], 0, 0, 0);
    acc[3][0] = __builtin_amdgcn_mfma_f32_16x16x32_f16(a3, b0, acc[3][0], 0, 0, 0);
    acc[0][1] = __builtin_amdgcn_mfma_f32_16x16x32_f16(a0, b1, acc[0][1], 0, 0, 0);
    acc[1][1] = __builtin_amdgcn_mfma_f32_16x16x32_f16(a1, b1, acc[1][1], 0, 0, 0);
    acc[2][1] = __builtin_amdgcn_mfma_f32_16x16x32_f16(a2, b1, acc[2][1], 0, 0, 0);
    acc[3][1] = __builtin_amdgcn_mfma_f32_16x16x32_f16(a3, b1, acc[3][1], 0, 0, 0);
  }

  const int col = lane & 15, qr = (lane >> 4) * 4;
  float* G = Gp + (size_t)z * (B_ * N3);
  #pragma unroll
  for (int nf = 0; nf < 2; ++nf) {
    int n = n0 + wn + nf * 16 + col;
    if (n >= N3) continue;
    #pragma unroll
    for (int mf = 0; mf < 4; ++mf)
      #pragma unroll
      for (int r = 0; r < 4; ++r)
        G[(size_t)(wm + mf * 16 + qr + r) * N3 + n] = acc[mf][nf][r];
  }
}

// ---- GRU gate update for step t ----
__global__ void gate_step(const float* __restrict__ Gp, const half_t* __restrict__ gx,
                          float* __restrict__ h, half_t* __restrict__ hh,
                          const int* __restrict__ lengths, float* __restrict__ out,
                          int t)
{
  int idx = blockIdx.x * 256 + threadIdx.x;   // over B_*H_
  int b = idx / H_;
  int j = idx - b * H_;

  size_t rx = ((size_t)b * S_ + t) * N3;
  float xr = (float)gx[rx + j];
  float xi = (float)gx[rx + H_ + j];
  float xn = (float)gx[rx + 2 * H_ + j];

  size_t gi = (size_t)b * N3;
  float Gr = 0.f, Gi = 0.f, Gn = 0.f;
  #pragma unroll
  for (int z = 0; z < ZSPLIT; ++z) {
    const float* Gz = Gp + (size_t)z * B_ * N3 + gi;
    Gr += Gz[j]; Gi += Gz[H_ + j]; Gn += Gz[2 * H_ + j];
  }

  float ho = h[idx];
  float r  = 1.f / (1.f + __expf(-(xr + Gr)));
  float ig = 1.f / (1.f + __expf(-(xi + Gi)));
  float n  = tanhf(xn + r * Gn);
  float hn = (1.f - ig) * n + ig * ho;

  h[idx]  = hn;
  hh[idx] = (half_t)hn;

  int lc = lengths[b] - 1;
  lc = lc < 0 ? 0 : (lc > S_ - 1 ? S_ - 1 : lc);
  if (t == lc) out[idx] = hn;
}

extern "C" void kernel_launch(void* const* d_in, const int* in_sizes, int n_in,
                              void* d_out, int out_size, void* d_ws, size_t ws_size,
                              hipStream_t stream)
{
  const int*   tokens  = (const int*)d_in[0];
  const int*   lengths = (const int*)d_in[1];
  const float* emb = (const float*)d_in[2];
  const float* Wir = (const float*)d_in[3];
  const float* Wii = (const float*)d_in[4];
  const float* Win = (const float*)d_in[5];
  const float* bir = (const float*)d_in[6];
  const float* bii = (const float*)d_in[7];
  const float* bin = (const float*)d_in[8];
  const float* Whr = (const float*)d_in[9];
  const float* Whi = (const float*)d_in[10];
  const float* Whn = (const float*)d_in[11];
  float* out = (float*)d_out;

  char* ws = (char*)d_ws;
  size_t off = 0;
  auto alloc = [&](size_t bytes) {
    void* p = ws + off;
    off = (off + bytes + 255) & ~(size_t)255;
    return p;
  };
  half_t* xb   = (half_t*)alloc((size_t)(B_ * S_) * EP * 2);   //  7.9 MB
  half_t* Wi   = (half_t*)alloc((size_t)N3 * EP * 2);          //  9.2 MB
  half_t* Wf   = (half_t*)alloc((size_t)N3 * KH * 2);          // 34.6 MB
  float*  bias = (float*)alloc((size_t)N3 * 4);
  half_t* gx   = (half_t*)alloc((size_t)(B_ * S_) * N3 * 2);   // 88.5 MB
  float*  Gp   = (float*)alloc((size_t)ZSPLIT * B_ * N3 * 4);  // 18.4 MB
  float*  h    = (float*)alloc((size_t)B_ * H_ * 4);
  half_t* hh   = (half_t*)alloc((size_t)B_ * H_ * 2);

  gather_cast_x<<<(B_ * S_ * EP) / 256, 256, 0, stream>>>(tokens, emb, xb);
  convert_wi<<<(N3 * EP) / 256, 256, 0, stream>>>(Wir, Wii, Win, bir, bii, bin, Wi, bias);
  convert_wh<<<(N3 * KH) / 256, 256, 0, stream>>>(Whr, Whi, Whn, Wf);
  init_h<<<(B_ * H_) / 256, 256, 0, stream>>>(h, hh);

  // Phase 1: gates_x = fp16( x @ W_i^T + b )   [6144 x 7200]
  gemm_x<<<dim3(48, 57), 256, 0, stream>>>(xb, Wi, gx, bias);

  // Phase 2: 48 sequential GRU steps, barrier-free LDS-free recurrent GEMM
  for (int t = 0; t < S_; ++t) {
    gemm_h<<<dim3(113, ZSPLIT), 256, 0, stream>>>(hh, Wf, Gp);
    gate_step<<<(B_ * H_) / 256, 256, 0, stream>>>(Gp, gx, h, hh, lengths, out, t);
  }
}